// Round 6
// baseline (5813.464 us; speedup 1.0000x reference)
//
#include <hip/hip_runtime.h>
#include <hip/hip_bf16.h>

// GCN forward: 2x GCNConv(128->128) + ELU + global mean pool + FC(128->1)
// R3/R4/R5: agg kernels were pegged at ~2TB/s random-gather transaction ceiling
// with a 255MB working set thrashing L3. Switch intermediate features to bf16:
// 256B rows, 51.2MB gather array = fully L3-resident, half the lines.
// 2-stage pipelined 16-deep asm gather (counted vmcnt(16), never 0 mid-chunk).
// (R5 = R3 resubmitted again: R3/R4 both hit GPUAcquisitionTimeout, never ran.)

#define NODES_PER_BLOCK 4   // waves per block in agg kernels

__device__ __forceinline__ unsigned int f32_to_bf16(float f) {
    unsigned int u = __float_as_uint(f);
    return (u + 0x7FFFu + ((u >> 16) & 1u)) >> 16;   // RNE
}
__device__ __forceinline__ float bf16lo(unsigned int u) { return __uint_as_float(u << 16); }
__device__ __forceinline__ float bf16hi(unsigned int u) { return __uint_as_float(u & 0xFFFF0000u); }

__global__ void init_kernel(float* __restrict__ deg, int* __restrict__ cnt,
                            float* __restrict__ gsum, int* __restrict__ gcnt, int n) {
    int i = blockIdx.x * blockDim.x + threadIdx.x;
    if (i < n) { deg[i] = 1.0f; cnt[i] = 0; }   // deg starts at 1.0 (self-loop weight)
    if (i < 64) { gsum[i] = 0.0f; gcnt[i] = 0; }
}

__global__ void edge_pass1(const int* __restrict__ dst, const float* __restrict__ ew,
                           float* __restrict__ deg, int* __restrict__ cnt, int E) {
    int e = blockIdx.x * blockDim.x + threadIdx.x;
    if (e >= E) return;
    int d = dst[e];
    atomicAdd(&deg[d], ew[e]);
    atomicAdd(&cnt[d], 1);
}

__global__ void compute_dinv(float* __restrict__ deg, int n) {
    int i = blockIdx.x * blockDim.x + threadIdx.x;
    if (i < n) deg[i] = rsqrtf(deg[i]);   // deg >= 1 always (self-loop)
}

// ---- 3-kernel exclusive scan of cnt -> rowptr ----
__global__ void scan_block(const int* __restrict__ cnt, int* __restrict__ rowptr,
                           int* __restrict__ partial, int n) {
    __shared__ int lds[256];
    int t = threadIdx.x;
    int i = blockIdx.x * 256 + t;
    int v = (i < n) ? cnt[i] : 0;
    lds[t] = v;
    __syncthreads();
    for (int off = 1; off < 256; off <<= 1) {
        int add = (t >= off) ? lds[t - off] : 0;
        __syncthreads();
        lds[t] += add;
        __syncthreads();
    }
    if (i < n) rowptr[i] = lds[t] - v;           // exclusive within block
    if (t == 255) partial[blockIdx.x] = lds[255]; // block total
}

__global__ void scan_partial(int* __restrict__ partial, int nb) {
    __shared__ int lds[1024];
    int t = threadIdx.x;
    int v = (t < nb) ? partial[t] : 0;
    lds[t] = v;
    __syncthreads();
    for (int off = 1; off < 1024; off <<= 1) {
        int add = (t >= off) ? lds[t - off] : 0;
        __syncthreads();
        lds[t] += add;
        __syncthreads();
    }
    if (t < nb) partial[t] = lds[t] - v;          // exclusive
}

__global__ void finalize_rowptr(int* __restrict__ rowptr, const int* __restrict__ partial,
                                int* __restrict__ cursor, int n, int e_total) {
    int i = blockIdx.x * 256 + threadIdx.x;
    if (i < n) {
        int v = rowptr[i] + partial[blockIdx.x];
        rowptr[i] = v;
        cursor[i] = v;
    }
    if (i == 0) rowptr[n] = e_total;
}

__global__ void edge_fill(const int* __restrict__ src, const int* __restrict__ dst,
                          const float* __restrict__ ew, const float* __restrict__ dinv,
                          int* __restrict__ cursor, int2* __restrict__ edges, int E) {
    int e = blockIdx.x * blockDim.x + threadIdx.x;
    if (e >= E) return;
    int s = src[e], d = dst[e];
    float w = dinv[s] * ew[e] * dinv[d];
    int pos = atomicAdd(&cursor[d], 1);
    edges[pos] = make_int2(s, __float_as_int(w));
}

// Y[n][col] = sum_k X[n][k] * W[k][col]. W column in registers per lane.
// BF16IN: X rows are 128 bf16 (256B); else 128 f32. Output bf16.
template <bool BF16IN>
__global__ __launch_bounds__(256, 2) void matmul_fc(const void* __restrict__ Xv,
                                                    const float* __restrict__ W,
                                                    unsigned short* __restrict__ Y, int n) {
    int wib = threadIdx.x >> 6, lane = threadIdx.x & 63;
    int wid = blockIdx.x * 4 + wib;
    int half = wid & 1;
    int col = (half << 6) | lane;
    float Wreg[128];
#pragma unroll
    for (int k = 0; k < 128; k++) Wreg[k] = W[k * 128 + col];
    int stride = (gridDim.x * 4) >> 1;
    for (int nn = wid >> 1; nn < n; nn += stride) {
        float a0 = 0.f, a1 = 0.f;
        if constexpr (BF16IN) {
            const uint4* xr = (const uint4*)((const char*)Xv + (size_t)nn * 256);
#pragma unroll
            for (int q = 0; q < 16; ++q) {
                uint4 u = xr[q];
                int k = q * 8;
                a0 = fmaf(bf16lo(u.x), Wreg[k + 0], a0); a1 = fmaf(bf16hi(u.x), Wreg[k + 1], a1);
                a0 = fmaf(bf16lo(u.y), Wreg[k + 2], a0); a1 = fmaf(bf16hi(u.y), Wreg[k + 3], a1);
                a0 = fmaf(bf16lo(u.z), Wreg[k + 4], a0); a1 = fmaf(bf16hi(u.z), Wreg[k + 5], a1);
                a0 = fmaf(bf16lo(u.w), Wreg[k + 6], a0); a1 = fmaf(bf16hi(u.w), Wreg[k + 7], a1);
            }
        } else {
            const float4* xr = (const float4*)((const float*)Xv + (size_t)nn * 128);
#pragma unroll
            for (int k4 = 0; k4 < 32; k4 += 2) {
                float4 xa = xr[k4];
                float4 xb = xr[k4 + 1];
                a0 = fmaf(xa.x, Wreg[4 * k4 + 0], a0);
                a0 = fmaf(xa.y, Wreg[4 * k4 + 1], a0);
                a0 = fmaf(xa.z, Wreg[4 * k4 + 2], a0);
                a0 = fmaf(xa.w, Wreg[4 * k4 + 3], a0);
                a1 = fmaf(xb.x, Wreg[4 * k4 + 4], a1);
                a1 = fmaf(xb.y, Wreg[4 * k4 + 5], a1);
                a1 = fmaf(xb.z, Wreg[4 * k4 + 6], a1);
                a1 = fmaf(xb.w, Wreg[4 * k4 + 7], a1);
            }
        }
        Y[(size_t)nn * 128 + col] = (unsigned short)f32_to_bf16(a0 + a1);
    }
}

// 2-stage pipelined 16-deep gather over one node's CSR edges. bf16 rows (256B);
// lane g-th gather: dword at H + (src<<8) + lane*4 = features {2lane, 2lane+1}.
__device__ __forceinline__ float2 gather_row_bf16(const unsigned short* __restrict__ H,
                                                  const int2* __restrict__ edges,
                                                  int beg, int end, int lane, float2 init) {
    float2 a0 = init;
    float2 a1 = make_float2(0.f, 0.f);
    float2 a2 = make_float2(0.f, 0.f);
    float2 a3 = make_float2(0.f, 0.f);
    const int lane4 = lane << 2;
    const unsigned long long hb = (unsigned long long)H;
    for (int base = beg; base < end; base += 64) {
        int cnt = end - base; if (cnt > 64) cnt = 64;
        int2 ed = make_int2(0, 0);               // pad: src=0, w=0.0f
        if (lane < cnt) ed = edges[base + lane];
        int es = ed.x;
        float ef = __int_as_float(ed.y);
        int nb = (cnt + 15) >> 4;                // 1..4 batches of 16
        unsigned int hA0,hA1,hA2_,hA3,hA4,hA5,hA6,hA7,hA8,hA9,hA10,hA11,hA12,hA13,hA14,hA15;
        unsigned int hB0,hB1,hB2,hB3,hB4,hB5,hB6,hB7,hB8,hB9,hB10,hB11,hB12,hB13,hB14,hB15;
        float wA0,wA1,wA2,wA3,wA4,wA5,wA6,wA7,wA8,wA9,wA10,wA11,wA12,wA13,wA14,wA15;
        float wB0,wB1,wB2,wB3,wB4,wB5,wB6,wB7,wB8,wB9,wB10,wB11,wB12,wB13,wB14,wB15;
        int o0,o1,o2,o3,o4,o5,o6,o7,o8,o9,o10,o11,o12,o13,o14,o15;

#define GRAB16(L, j) \
    o0=(__shfl(es,(j)+0)<<8)|lane4;  w##L##0=__shfl(ef,(j)+0); \
    o1=(__shfl(es,(j)+1)<<8)|lane4;  w##L##1=__shfl(ef,(j)+1); \
    o2=(__shfl(es,(j)+2)<<8)|lane4;  w##L##2=__shfl(ef,(j)+2); \
    o3=(__shfl(es,(j)+3)<<8)|lane4;  w##L##3=__shfl(ef,(j)+3); \
    o4=(__shfl(es,(j)+4)<<8)|lane4;  w##L##4=__shfl(ef,(j)+4); \
    o5=(__shfl(es,(j)+5)<<8)|lane4;  w##L##5=__shfl(ef,(j)+5); \
    o6=(__shfl(es,(j)+6)<<8)|lane4;  w##L##6=__shfl(ef,(j)+6); \
    o7=(__shfl(es,(j)+7)<<8)|lane4;  w##L##7=__shfl(ef,(j)+7); \
    o8=(__shfl(es,(j)+8)<<8)|lane4;  w##L##8=__shfl(ef,(j)+8); \
    o9=(__shfl(es,(j)+9)<<8)|lane4;  w##L##9=__shfl(ef,(j)+9); \
    o10=(__shfl(es,(j)+10)<<8)|lane4; w##L##10=__shfl(ef,(j)+10); \
    o11=(__shfl(es,(j)+11)<<8)|lane4; w##L##11=__shfl(ef,(j)+11); \
    o12=(__shfl(es,(j)+12)<<8)|lane4; w##L##12=__shfl(ef,(j)+12); \
    o13=(__shfl(es,(j)+13)<<8)|lane4; w##L##13=__shfl(ef,(j)+13); \
    o14=(__shfl(es,(j)+14)<<8)|lane4; w##L##14=__shfl(ef,(j)+14); \
    o15=(__shfl(es,(j)+15)<<8)|lane4; w##L##15=__shfl(ef,(j)+15);

#define ISSUE8(d0,d1,d2,d3,d4,d5,d6,d7, s0,s1,s2,s3,s4,s5,s6,s7) \
    asm volatile( \
        "global_load_dword %0, %8,  %16\n\t" \
        "global_load_dword %1, %9,  %16\n\t" \
        "global_load_dword %2, %10, %16\n\t" \
        "global_load_dword %3, %11, %16\n\t" \
        "global_load_dword %4, %12, %16\n\t" \
        "global_load_dword %5, %13, %16\n\t" \
        "global_load_dword %6, %14, %16\n\t" \
        "global_load_dword %7, %15, %16" \
        : "=&v"(d0), "=&v"(d1), "=&v"(d2), "=&v"(d3), \
          "=&v"(d4), "=&v"(d5), "=&v"(d6), "=&v"(d7) \
        : "v"(s0), "v"(s1), "v"(s2), "v"(s3), \
          "v"(s4), "v"(s5), "v"(s6), "v"(s7), "s"(hb));

#define ISSUE_A ISSUE8(hA0,hA1,hA2_,hA3,hA4,hA5,hA6,hA7, o0,o1,o2,o3,o4,o5,o6,o7) \
                ISSUE8(hA8,hA9,hA10,hA11,hA12,hA13,hA14,hA15, o8,o9,o10,o11,o12,o13,o14,o15)
#define ISSUE_B ISSUE8(hB0,hB1,hB2,hB3,hB4,hB5,hB6,hB7, o0,o1,o2,o3,o4,o5,o6,o7) \
                ISSUE8(hB8,hB9,hB10,hB11,hB12,hB13,hB14,hB15, o8,o9,o10,o11,o12,o13,o14,o15)

#define WAIT16 asm volatile("s_waitcnt vmcnt(16)" ::: "memory"); __builtin_amdgcn_sched_barrier(0);
#define WAIT0  asm volatile("s_waitcnt vmcnt(0)"  ::: "memory"); __builtin_amdgcn_sched_barrier(0);

#define ACC1(L, g, ac) ac.x = fmaf(w##L##g, bf16lo(h##L##g), ac.x); \
                       ac.y = fmaf(w##L##g, bf16hi(h##L##g), ac.y);
#define FMA_A ACC1(A,0,a0) ACC1(A,1,a1) ACC1(A,2_,a2) ACC1(A,3,a3) \
              ACC1(A,4,a0) ACC1(A,5,a1) ACC1(A,6,a2)  ACC1(A,7,a3) \
              ACC1(A,8,a0) ACC1(A,9,a1) ACC1(A,10,a2) ACC1(A,11,a3) \
              ACC1(A,12,a0) ACC1(A,13,a1) ACC1(A,14,a2) ACC1(A,15,a3)
#define FMA_B ACC1(B,0,a0) ACC1(B,1,a1) ACC1(B,2,a2)  ACC1(B,3,a3) \
              ACC1(B,4,a0) ACC1(B,5,a1) ACC1(B,6,a2)  ACC1(B,7,a3) \
              ACC1(B,8,a0) ACC1(B,9,a1) ACC1(B,10,a2) ACC1(B,11,a3) \
              ACC1(B,12,a0) ACC1(B,13,a1) ACC1(B,14,a2) ACC1(B,15,a3)

        // wA2 name quirk: hA2_ pairs with wA2_ — declare alias
        float wA2_ = 0.f;
        if (nb == 1) {
            GRAB16(A, 0) wA2_ = wA2; ISSUE_A
            WAIT0 FMA_A
        } else if (nb == 2) {
            GRAB16(A, 0) wA2_ = wA2; ISSUE_A
            GRAB16(B, 16) ISSUE_B
            WAIT16 FMA_A
            WAIT0  FMA_B
        } else if (nb == 3) {
            GRAB16(A, 0) wA2_ = wA2; ISSUE_A
            GRAB16(B, 16) ISSUE_B
            WAIT16 FMA_A
            GRAB16(A, 32) wA2_ = wA2; ISSUE_A
            WAIT16 FMA_B
            WAIT0  FMA_A
        } else {
            GRAB16(A, 0) wA2_ = wA2; ISSUE_A
            GRAB16(B, 16) ISSUE_B
            WAIT16 FMA_A
            GRAB16(A, 32) wA2_ = wA2; ISSUE_A
            WAIT16 FMA_B
            GRAB16(B, 48) ISSUE_B
            WAIT16 FMA_A
            WAIT0  FMA_B
        }
#undef GRAB16
#undef ISSUE8
#undef ISSUE_A
#undef ISSUE_B
#undef WAIT16
#undef WAIT0
#undef ACC1
#undef FMA_A
#undef FMA_B
    }
    a0.x += a1.x + a2.x + a3.x;
    a0.y += a1.y + a2.y + a3.y;
    return a0;
}

// Aggregation layer 1: out = ELU( dinv^2*H[n] + sum_e w_e*H[src_e] + b1 ), bf16 in/out
__global__ __launch_bounds__(256, 4) void agg_elu(const unsigned short* __restrict__ H,
                                                  const int2* __restrict__ edges,
                                                  const int* __restrict__ rowptr,
                                                  const float* __restrict__ dinv,
                                                  const float* __restrict__ bias,
                                                  unsigned short* __restrict__ out, int n) {
    int w = threadIdx.x >> 6, lane = threadIdx.x & 63;
    int node = blockIdx.x * NODES_PER_BLOCK + w;
    if (node >= n) return;
    float di = dinv[node];
    float sw = di * di;
    unsigned int ow = ((const unsigned int*)H)[(size_t)node * 64 + lane];
    float2 acc = gather_row_bf16(H, edges, rowptr[node], rowptr[node + 1], lane,
                                 make_float2(bf16lo(ow) * sw, bf16hi(ow) * sw));
    float ox = acc.x + bias[2 * lane];
    float oy = acc.y + bias[2 * lane + 1];
    ox = ox > 0.f ? ox : expm1f(ox);
    oy = oy > 0.f ? oy : expm1f(oy);
    ((unsigned int*)out)[(size_t)node * 64 + lane] = f32_to_bf16(ox) | (f32_to_bf16(oy) << 16);
}

// Aggregation layer 2 fused with pooling.
__global__ __launch_bounds__(256, 4) void agg_pool(const unsigned short* __restrict__ H,
                                                   const int2* __restrict__ edges,
                                                   const int* __restrict__ rowptr,
                                                   const float* __restrict__ dinv,
                                                   const float* __restrict__ bias,
                                                   const float* __restrict__ wfc,
                                                   const int* __restrict__ batch,
                                                   float* __restrict__ gsum,
                                                   int* __restrict__ gcnt, int n) {
    int w = threadIdx.x >> 6, lane = threadIdx.x & 63;
    int node = blockIdx.x * NODES_PER_BLOCK + w;
    if (node >= n) return;
    float di = dinv[node];
    float sw = di * di;
    unsigned int ow = ((const unsigned int*)H)[(size_t)node * 64 + lane];
    float2 acc = gather_row_bf16(H, edges, rowptr[node], rowptr[node + 1], lane,
                                 make_float2(bf16lo(ow) * sw, bf16hi(ow) * sw));
    float px = acc.x + bias[2 * lane];
    float py = acc.y + bias[2 * lane + 1];
    float partial = px * wfc[2 * lane] + py * wfc[2 * lane + 1];
#pragma unroll
    for (int off = 32; off; off >>= 1) partial += __shfl_xor(partial, off);
    if (lane == 0) {
        int g = batch[node];
        atomicAdd(&gsum[g], partial);
        atomicAdd(&gcnt[g], 1);
    }
}

__global__ void finalize_out(const float* __restrict__ gsum, const int* __restrict__ gcnt,
                             const float* __restrict__ bfc, float* __restrict__ out) {
    int g = threadIdx.x;
    if (g < 64) {
        float c = (float)gcnt[g];
        out[g] = gsum[g] / fmaxf(c, 1.0f) + bfc[0];
    }
}

extern "C" void kernel_launch(void* const* d_in, const int* in_sizes, int n_in,
                              void* d_out, int out_size, void* d_ws, size_t ws_size,
                              hipStream_t stream) {
    const int N = in_sizes[0] / 128;       // 200000
    const int E = in_sizes[2];             // 6400000

    const float* x     = (const float*)d_in[0];
    const int*   ei    = (const int*)d_in[1];
    const int*   src   = ei;
    const int*   dst   = ei + E;
    const float* ew    = (const float*)d_in[2];
    const int*   batch = (const int*)d_in[3];
    const float* W1    = (const float*)d_in[4];
    const float* b1    = (const float*)d_in[5];
    const float* W2    = (const float*)d_in[6];
    const float* b2    = (const float*)d_in[7];
    const float* Wfc   = (const float*)d_in[8];
    const float* bfc   = (const float*)d_in[9];
    float* out = (float*)d_out;

    // workspace carve (256B aligned)
    char* base = (char*)d_ws;
    size_t off = 0;
    auto carve = [&](size_t bytes) -> void* {
        void* r = base + off;
        off = (off + bytes + 255) & ~(size_t)255;
        return r;
    };
    unsigned short* t1 = (unsigned short*)carve((size_t)N * 128 * 2);  // matmul out (both layers)
    unsigned short* t2 = (unsigned short*)carve((size_t)N * 128 * 2);  // agg_elu out
    int2*  edges   = (int2*) carve((size_t)E * 8);
    float* deg     = (float*)carve((size_t)N * 4);     // becomes dinv in place
    int*   rowptr  = (int*)  carve((size_t)(N + 1) * 4);
    int*   cursor  = (int*)  carve((size_t)N * 4);     // counts, then fill cursors
    int*   partial = (int*)  carve(1024 * 4);
    float* gsum    = (float*)carve(64 * 4);
    int*   gcnt    = (int*)  carve(64 * 4);

    const int NB = (N + 255) / 256;        // 782 scan blocks (<=1024)
    const int EB = (E + 255) / 256;
    const int AGGB = (N + NODES_PER_BLOCK - 1) / NODES_PER_BLOCK;

    hipLaunchKernelGGL(init_kernel, dim3(NB), dim3(256), 0, stream, deg, cursor, gsum, gcnt, N);
    hipLaunchKernelGGL(edge_pass1, dim3(EB), dim3(256), 0, stream, dst, ew, deg, cursor, E);
    hipLaunchKernelGGL(compute_dinv, dim3(NB), dim3(256), 0, stream, deg, N);
    hipLaunchKernelGGL(scan_block, dim3(NB), dim3(256), 0, stream, cursor, rowptr, partial, N);
    hipLaunchKernelGGL(scan_partial, dim3(1), dim3(1024), 0, stream, partial, NB);
    hipLaunchKernelGGL(finalize_rowptr, dim3(NB), dim3(256), 0, stream, rowptr, partial, cursor, N, E);
    hipLaunchKernelGGL(edge_fill, dim3(EB), dim3(256), 0, stream, src, dst, ew, deg, cursor, edges, E);
    // layer 1
    hipLaunchKernelGGL((matmul_fc<false>), dim3(2048), dim3(256), 0, stream, (const void*)x, W1, t1, N);
    hipLaunchKernelGGL(agg_elu, dim3(AGGB), dim3(256), 0, stream, t1, edges, rowptr, deg, b1, t2, N);
    // layer 2
    hipLaunchKernelGGL((matmul_fc<true>), dim3(2048), dim3(256), 0, stream, (const void*)t2, W2, t1, N);
    hipLaunchKernelGGL(agg_pool, dim3(AGGB), dim3(256), 0, stream, t1, edges, rowptr, deg, b2, Wfc, batch, gsum, gcnt, N);
    // pool finalize
    hipLaunchKernelGGL(finalize_out, dim3(1), dim3(64), 0, stream, gsum, gcnt, bfc, out);
}